// Round 15
// baseline (605.311 us; speedup 1.0000x reference)
//
#include <hip/hip_runtime.h>
#include <hip/hip_bf16.h>
#include <math.h>

// Problem constants
#define DD   2048
#define SS   2048
#define HH   16
#define HDIM 128
#define BB   2
#define MM   4096   // B*S rows
#define D4   8192

using bf16x8 = __attribute__((ext_vector_type(8))) short;
using f32x4  = __attribute__((ext_vector_type(4))) float;
using f32x16 = __attribute__((ext_vector_type(16))) float;

__device__ __forceinline__ ushort f2bf(float x) {
  uint u = __builtin_bit_cast(uint, x);
  u += 0x7FFFu + ((u >> 16) & 1u);   // round-to-nearest-even
  return (ushort)(u >> 16);
}
__device__ __forceinline__ float bf2f(ushort u) {
  return __builtin_bit_cast(float, (uint)u << 16);
}
__device__ __forceinline__ uint pkbf2(float a, float b) {
  return (uint)f2bf(a) | ((uint)f2bf(b) << 16);
}

__device__ __forceinline__ float gelu_f(float v) {
  float u = 0.7978845608028654f * (v + 0.044715f * v * v * v);
  float e = __expf(2.0f * u);
  float th = 1.0f - 2.0f / (e + 1.0f);   // robust tanh (inf-safe)
  return 0.5f * v * (1.0f + th);
}

__device__ __forceinline__ void gload_lds16(const void* g, void* l) {
  __builtin_amdgcn_global_load_lds(
      (const __attribute__((address_space(1))) void*)g,
      (__attribute__((address_space(3))) void*)l, 16, 0, 0);
}

// ---------------------------------------------------------------- f32 -> bf16
// 4-way merged conversion; dst segments contiguous. SHIFT: blocks per seg.
template <int SHIFT>
__global__ __launch_bounds__(256) void cvt4_f32_bf16(
    const float* __restrict__ s0, const float* __restrict__ s1,
    const float* __restrict__ s2, const float* __restrict__ s3,
    ushort* __restrict__ dst) {
  int seg = blockIdx.x >> SHIFT;
  int i = ((blockIdx.x & ((1 << SHIFT) - 1)) << 8) + threadIdx.x;
  const float* src = (seg == 0) ? s0 : (seg == 1) ? s1 : (seg == 2) ? s2 : s3;
  float4 v = ((const float4*)src)[i];
  ushort4 o;
  o.x = f2bf(v.x); o.y = f2bf(v.y); o.z = f2bf(v.z); o.w = f2bf(v.w);
  ((ushort4*)dst)[((size_t)seg << (SHIFT + 8)) + i] = o;
}

// ---------------------------------------------------------------- LayerNorm
template <bool BIN>
__global__ __launch_bounds__(256) void ln_rows(
    const void* __restrict__ inp, const float* __restrict__ gam,
    const float* __restrict__ bet, ushort* __restrict__ outb) {
  int row = blockIdx.x;
  int t = threadIdx.x;
  float v[8];
  if (BIN) {
    const ushort4* r4 = (const ushort4*)((const ushort*)inp + (size_t)row * DD);
    ushort4 a = r4[t * 2], b = r4[t * 2 + 1];
    v[0] = bf2f(a.x); v[1] = bf2f(a.y); v[2] = bf2f(a.z); v[3] = bf2f(a.w);
    v[4] = bf2f(b.x); v[5] = bf2f(b.y); v[6] = bf2f(b.z); v[7] = bf2f(b.w);
  } else {
    const float4* r4 = (const float4*)((const float*)inp + (size_t)row * DD);
    float4 a = r4[t * 2], b = r4[t * 2 + 1];
    v[0] = a.x; v[1] = a.y; v[2] = a.z; v[3] = a.w;
    v[4] = b.x; v[5] = b.y; v[6] = b.z; v[7] = b.w;
  }
  float s = ((v[0] + v[1]) + (v[2] + v[3])) + ((v[4] + v[5]) + (v[6] + v[7]));
  __shared__ float redA[4], redB[4];
  #pragma unroll
  for (int off = 32; off >= 1; off >>= 1) s += __shfl_xor(s, off);
  if ((t & 63) == 0) redA[t >> 6] = s;
  __syncthreads();
  float mean = (redA[0] + redA[1] + redA[2] + redA[3]) * (1.0f / DD);
  float q = 0.f;
  #pragma unroll
  for (int i = 0; i < 8; i++) { v[i] -= mean; q += v[i] * v[i]; }
  #pragma unroll
  for (int off = 32; off >= 1; off >>= 1) q += __shfl_xor(q, off);
  if ((t & 63) == 0) redB[t >> 6] = q;
  __syncthreads();
  float var = (redB[0] + redB[1] + redB[2] + redB[3]) * (1.0f / DD);
  float rstd = rsqrtf(var + 1e-5f);
  const float4* g4 = (const float4*)gam;
  const float4* b4 = (const float4*)bet;
  float4 g0 = g4[t * 2], g1 = g4[t * 2 + 1];
  float4 bb0 = b4[t * 2], bb1 = b4[t * 2 + 1];
  ushort4 u0, u1;
  u0.x = f2bf(v[0] * rstd * g0.x + bb0.x);
  u0.y = f2bf(v[1] * rstd * g0.y + bb0.y);
  u0.z = f2bf(v[2] * rstd * g0.z + bb0.z);
  u0.w = f2bf(v[3] * rstd * g0.w + bb0.w);
  u1.x = f2bf(v[4] * rstd * g1.x + bb1.x);
  u1.y = f2bf(v[5] * rstd * g1.y + bb1.y);
  u1.z = f2bf(v[6] * rstd * g1.z + bb1.z);
  u1.w = f2bf(v[7] * rstd * g1.w + bb1.w);
  ushort4* ob4 = (ushort4*)(outb + (size_t)row * DD);
  ob4[t * 2] = u0; ob4[t * 2 + 1] = u1;
}

// ---------------------------------------------------------------- GEMM (r3)
// Verified r3..r14. Used for QKV + Wo. vmcnt-only tile wait.
template <int OMODE, bool GELU_, bool RES_>
__global__ __launch_bounds__(512, 2) void gemm2(
    const ushort* __restrict__ A, const ushort* __restrict__ Bt,
    const float* __restrict__ pb0, const float* __restrict__ pb1,
    const float* __restrict__ pb2, const ushort* __restrict__ res,
    void* __restrict__ Cout, int M, int N, int K) {
  extern __shared__ __align__(16) ushort smem[];   // 3 * (16384 + 8192)
  const int nbm = M >> 8, nbn = N >> 7;
  const int nwg = nbm * nbn;
  int wg = blockIdx.x;
  int wg2 = (wg & 7) * (nwg >> 3) + (wg >> 3);     // bijective XCD swizzle
  int bm = wg2 % nbm, bn = wg2 / nbm;
  int m0 = bm << 8, n0 = bn << 7;
  int t = threadIdx.x, lane = t & 63, w = t >> 6;
  int wm = w >> 2, wn = w & 3;
  int lr = lane & 15, lg = lane >> 4;

  auto stage = [&](int kt, int slot) {
    int k0 = kt << 6;
    ushort* lA = smem + slot * 24576;
    ushort* lB = lA + 16384;
    #pragma unroll
    for (int r = 0; r < 4; r++) {
      int idx = (r << 9) + t;
      int row = idx >> 3, ch = idx & 7;
      gload_lds16(A + (size_t)(m0 + row) * K + k0 + ((ch ^ (row & 7)) << 3),
                  lA + idx * 8);
    }
    #pragma unroll
    for (int r = 0; r < 2; r++) {
      int idx = (r << 9) + t;
      int row = idx >> 3, ch = idx & 7;
      gload_lds16(Bt + (size_t)(n0 + row) * K + k0 + ((ch ^ (row & 7)) << 3),
                  lB + idx * 8);
    }
  };

  f32x4 acc[8][2] = {};
  const int NT = K >> 6;
  stage(0, 0);
  stage(1, 1);
  int slot = 0;
  for (int kt = 0; kt < NT; ++kt) {
    __builtin_amdgcn_sched_barrier(0);
    if (kt + 1 < NT)
      asm volatile("s_waitcnt vmcnt(6)" ::: "memory");
    else
      asm volatile("s_waitcnt vmcnt(0)" ::: "memory");
    __builtin_amdgcn_s_barrier();
    __builtin_amdgcn_sched_barrier(0);
    if (kt + 2 < NT) {
      int s2 = slot + 2; if (s2 >= 3) s2 -= 3;
      stage(kt + 2, s2);
    }
    const ushort* lA = smem + slot * 24576;
    const ushort* lB = lA + 16384;
    bf16x8 af[8][2], bfr[2][2];
    #pragma unroll
    for (int mi = 0; mi < 8; mi++) {
      int row = wm * 128 + mi * 16 + lr;
      #pragma unroll
      for (int ks = 0; ks < 2; ks++)
        af[mi][ks] = *(const bf16x8*)
            &lA[row * 64 + (((ks * 4 + lg) ^ (row & 7)) << 3)];
    }
    #pragma unroll
    for (int ni = 0; ni < 2; ni++) {
      int row = wn * 32 + ni * 16 + lr;
      #pragma unroll
      for (int ks = 0; ks < 2; ks++)
        bfr[ni][ks] = *(const bf16x8*)
            &lB[row * 64 + (((ks * 4 + lg) ^ (row & 7)) << 3)];
    }
    __builtin_amdgcn_s_setprio(1);
    #pragma unroll
    for (int ks = 0; ks < 2; ks++)
      #pragma unroll
      for (int mi = 0; mi < 8; mi++)
        #pragma unroll
        for (int ni = 0; ni < 2; ni++)
          acc[mi][ni] = __builtin_amdgcn_mfma_f32_16x16x32_bf16(
              af[mi][ks], bfr[ni][ks], acc[mi][ni], 0, 0, 0);
    __builtin_amdgcn_s_setprio(0);
    slot = (slot + 1 == 3) ? 0 : slot + 1;
  }

  if (OMODE == 3) {
    // fused QKV routing; seg uniform per block (2048 % 128 == 0)
    int seg = n0 >> 11;
    const float* pb = (seg == 0) ? pb0 : (seg == 1) ? pb1 : pb2;
    int c0 = n0 & 2047;
    float bv[2];
    #pragma unroll
    for (int ni = 0; ni < 2; ni++) bv[ni] = pb[c0 + wn * 32 + ni * 16 + lr];
    if (seg < 2) {
      ushort* q_or_k = (ushort*)Cout + (size_t)seg * MM * DD;
      #pragma unroll
      for (int mi = 0; mi < 8; mi++) {
        #pragma unroll
        for (int r = 0; r < 4; r++) {
          int m = m0 + wm * 128 + mi * 16 + lg * 4 + r;
          #pragma unroll
          for (int ni = 0; ni < 2; ni++) {
            int col = c0 + wn * 32 + ni * 16 + lr;
            q_or_k[(size_t)m * DD + col] = f2bf(acc[mi][ni][r] + bv[ni]);
          }
        }
      }
    } else {
      // V^T: vT[(b*16+h)][d][s], ushort4 along s (4 consecutive m)
      ushort* vT = (ushort*)Cout + (size_t)2 * MM * DD;
      #pragma unroll
      for (int mi = 0; mi < 8; mi++) {
        int mg = m0 + wm * 128 + mi * 16 + lg * 4;
        int bb_ = mg >> 11, sb = mg & 2047;
        #pragma unroll
        for (int ni = 0; ni < 2; ni++) {
          int col = c0 + wn * 32 + ni * 16 + lr;
          int h = col >> 7, d = col & 127;
          ushort4 u4;
          u4.x = f2bf(acc[mi][ni][0] + bv[ni]);
          u4.y = f2bf(acc[mi][ni][1] + bv[ni]);
          u4.z = f2bf(acc[mi][ni][2] + bv[ni]);
          u4.w = f2bf(acc[mi][ni][3] + bv[ni]);
          size_t idx = ((size_t)(bb_ * 16 + h) * 128 + d) * 2048 + sb;
          *(ushort4*)&vT[idx] = u4;
        }
      }
    }
    return;
  }

  float bv[2];
  #pragma unroll
  for (int ni = 0; ni < 2; ni++) bv[ni] = pb0[n0 + wn * 32 + ni * 16 + lr];
  #pragma unroll
  for (int mi = 0; mi < 8; mi++) {
    #pragma unroll
    for (int r = 0; r < 4; r++) {
      int m = m0 + wm * 128 + mi * 16 + lg * 4 + r;
      #pragma unroll
      for (int ni = 0; ni < 2; ni++) {
        int n = n0 + wn * 32 + ni * 16 + lr;
        size_t idx = (size_t)m * N + n;
        float v = acc[mi][ni][r] + bv[ni];
        if (RES_) v += bf2f(res[idx]);
        if (GELU_) v = gelu_f(v);
        if (OMODE == 1) ((ushort*)Cout)[idx] = f2bf(v);
        else            ((float*)Cout)[idx] = v;
      }
    }
  }
}

// ---------------------------------------------------------------- GEMM v8.5
// 256x256, 2-barrier software-pipelined tile. Quadrant order Q00,Q01,Q11,Q10:
// R1{16 reads (aR1,bR0,bR1) || Q00+Q01}  [sched_barrier: aR reg-reuse]
// R2{8 reads aR2 || Q11}  -> BAR_mid (program order: every wave's MFMAs
//   consumed all 24 reads => whole current buffer free)
// R3{stage4(kt+2): 8 gloads into freed buffer || Q10 reg-only}
//   vmcnt(8) [FIFO => kt+1 landed]  -> BAR_end.
// OMODE: 1 = bf16 out (+gelu), 4 = split-K bf16 partial.
#define MF16(MQ, NQ, BARR) \
  { _Pragma("unroll") for (int ks = 0; ks < 2; ks++) { \
    _Pragma("unroll") for (int fm = 0; fm < 4; fm++) { \
      _Pragma("unroll") for (int fn = 0; fn < 2; fn++) { \
        acc[MQ * 4 + fm][NQ * 2 + fn] = \
            __builtin_amdgcn_mfma_f32_16x16x32_bf16( \
                aR[fm][ks], BARR[fn][ks], acc[MQ * 4 + fm][NQ * 2 + fn], \
                0, 0, 0); } } } }

template <int OMODE, bool GELU_>
__global__ __launch_bounds__(512, 2) void gemm8(
    const ushort* __restrict__ A, const ushort* __restrict__ Bt,
    const float* __restrict__ pb0,
    void* __restrict__ Cout, int M, int N, int Kfull, int Kloc) {
  extern __shared__ __align__(16) ushort smem[];   // 65536 elem = 128 KB
  const int nbm = M >> 8, nbn = N >> 8;
  const int nwg = nbm * nbn;
  int wgr = blockIdx.x;
  int ksl = 0;
  if (OMODE == 4) { ksl = wgr / nwg; wgr -= ksl * nwg; }
  int wg2 = (wgr & 7) * (nwg >> 3) + (wgr >> 3);   // bijective XCD swizzle
  int bm = wg2 % nbm, bn = wg2 / nbm;
  int m0 = bm << 8, n0 = bn << 8;
  size_t kbase = (size_t)ksl * Kloc;
  int t = threadIdx.x, lane = t & 63, w = t >> 6;
  int wm = w >> 2, wn = w & 3;
  int lr = lane & 15, lg = lane >> 4;

  // staging source bases (phase-consumption row remap, src pre-swizzle)
  int srow = t >> 3;
  int ssw = ((t & 7) ^ (srow & 7)) << 3;
  const ushort* pA1 = A + (size_t)(m0 + srow) * Kfull + kbase + ssw;
  const ushort* pB1 = Bt +
      (size_t)(n0 + (srow >> 5) * 64 + (srow & 31)) * Kfull + kbase + ssw;
  const size_t K32 = (size_t)32 * Kfull, K64 = (size_t)64 * Kfull,
               K128 = (size_t)128 * Kfull;
  ushort* dA = smem + t * 8;
  ushort* dB = smem + 16384 + t * 8;

  // stage all 4 halves of tile kt (8 gloads)
  auto stage4 = [&](int kt) {
    int boff = (kt & 1) << 15;
    size_t ko = (size_t)kt << 6;
    gload_lds16(pA1 + ko, dA + boff);
    gload_lds16(pA1 + K128 + ko, dA + boff + 4096);
    gload_lds16(pA1 + K64 + ko, dA + boff + 8192);
    gload_lds16(pA1 + K64 + K128 + ko, dA + boff + 12288);
    gload_lds16(pB1 + ko, dB + boff);
    gload_lds16(pB1 + K128 + ko, dB + boff + 4096);
    gload_lds16(pB1 + K32 + ko, dB + boff + 8192);
    gload_lds16(pB1 + K32 + K128 + ko, dB + boff + 12288);
  };

  int swz0 = (lg ^ (lr & 7)) << 3;
  int swz1 = ((4 + lg) ^ (lr & 7)) << 3;
  int arb[4], brb[2];
  #pragma unroll
  for (int f = 0; f < 4; f++) arb[f] = (wm * 64 + f * 16 + lr) * 64;
  #pragma unroll
  for (int f = 0; f < 2; f++) brb[f] = (wn * 32 + f * 16 + lr) * 64;

  f32x4 acc[8][4] = {};
  bf16x8 aR[4][2], bR0[2][2], bR1[2][2];
  const int NT = Kloc >> 6;

  stage4(0); stage4(1);
  asm volatile("s_waitcnt vmcnt(8)" ::: "memory");   // tile 0 landed
  __builtin_amdgcn_s_barrier();
  __builtin_amdgcn_sched_barrier(0);

  for (int kt = 0; kt < NT; ++kt) {
    const ushort* hA = smem + ((kt & 1) << 15);
    const ushort* hB = hA + 16384;
    bool st2 = (kt + 2 < NT);
    // ---- R1: 16 reads (aR-first, bR0, bR1) || Q00 + Q01
    __builtin_amdgcn_s_setprio(1);
    #pragma unroll
    for (int f = 0; f < 4; f++) {
      aR[f][0] = *(const bf16x8*)&hA[arb[f] + swz0];
      aR[f][1] = *(const bf16x8*)&hA[arb[f] + swz1];
    }
    #pragma unroll
    for (int f = 0; f < 2; f++) {
      bR0[f][0] = *(const bf16x8*)&hB[brb[f] + swz0];
      bR0[f][1] = *(const bf16x8*)&hB[brb[f] + swz1];
      bR1[f][0] = *(const bf16x8*)&hB[8192 + brb[f] + swz0];
      bR1[f][1] = *(const bf16x8*)&hB[8192 + brb[f] + swz1];
    }
    MF16(0, 0, bR0);
    MF16(0, 1, bR1);
    __builtin_amdgcn_s_setprio(0);
    __builtin_amdgcn_sched_barrier(0);   // aR2 reads stay below (reg reuse)
    // ---- R2: 8 reads (aR-second, reusing aR regs) || Q11
    __builtin_amdgcn_s_setprio(1);
    #pragma unroll
    for (int f = 0; f < 4; f++) {
      aR[f][0] = *(const bf16x8*)&hA[8192 + arb[f] + swz0];
      aR[f][1] = *(const bf16x8*)&hA[8192 + arb[f] + swz1];
    }
    MF16(1, 1, bR1);
    __builtin_amdgcn_s_setprio(0);
    __builtin_amdgcn_sched_barrier(0);
    __builtin_amdgcn_s_barrier();        // BAR_mid: all reads consumed
    __builtin_amdgcn_sched_barrier(0);
    // ---- R3: stage tile kt+2 into freed buffer || Q10 (reg-only)
    if (st2) stage4(kt + 2);
    __builtin_amdgcn_s_setprio(1);
    MF16(1, 0, bR0);
    __builtin_amdgcn_s_setprio(0);
    __builtin_amdgcn_sched_barrier(0);
    if (st2)              { asm volatile("s_waitcnt vmcnt(8)" ::: "memory"); }
    else if (kt + 1 < NT) { asm volatile("s_waitcnt vmcnt(0)" ::: "memory"); }
    __builtin_amdgcn_s_barrier();        // BAR_end (tile kt+1 ready)
    __builtin_amdgcn_sched_barrier(0);
  }

  if constexpr (OMODE == 4) {
    // split-K bf16 partial, no bias
    ushort* Cp = (ushort*)Cout + (size_t)ksl * M * N;
    #pragma unroll
    for (int mi = 0; mi < 8; mi++) {
      #pragma unroll
      for (int r = 0; r < 4; r++) {
        int m = m0 + wm * 128 + mi * 16 + lg * 4 + r;
        #pragma unroll
        for (int ni = 0; ni < 4; ni++) {
          int n = n0 + wn * 64 + ni * 16 + lr;
          Cp[(size_t)m * N + n] = f2bf(acc[mi][ni][r]);
        }
      }
    }
  } else {
    float bv[4];
    #pragma unroll
    for (int ni = 0; ni < 4; ni++) bv[ni] = pb0[n0 + wn * 64 + ni * 16 + lr];
    #pragma unroll
    for (int mi = 0; mi < 8; mi++) {
      #pragma unroll
      for (int r = 0; r < 4; r++) {
        int m = m0 + wm * 128 + mi * 16 + lg * 4 + r;
        #pragma unroll
        for (int ni = 0; ni < 4; ni++) {
          int n = n0 + wn * 64 + ni * 16 + lr;
          float v = acc[mi][ni][r] + bv[ni];
          if (GELU_) v = gelu_f(v);
          ((ushort*)Cout)[(size_t)m * N + n] = f2bf(v);
        }
      }
    }
  }
}

// ---------------------------------------------------------------- combine
// out(f32) = p0 + p1 + bias[n] + bf16 residual  (MLP-down split-K)
__global__ __launch_bounds__(256) void mlp_fin(
    const ushort* __restrict__ p, const ushort* __restrict__ res,
    const float* __restrict__ bias, float* __restrict__ out) {
  int i4 = blockIdx.x * 256 + threadIdx.x;
  ushort4 a = ((const ushort4*)p)[i4];
  ushort4 b = ((const ushort4*)(p + (size_t)MM * DD))[i4];
  ushort4 r = ((const ushort4*)res)[i4];
  float4 g = ((const float4*)bias)[i4 & 511];
  float4 o;
  o.x = bf2f(a.x) + bf2f(b.x) + bf2f(r.x) + g.x;
  o.y = bf2f(a.y) + bf2f(b.y) + bf2f(r.y) + g.y;
  o.z = bf2f(a.z) + bf2f(b.z) + bf2f(r.z) + g.z;
  o.w = bf2f(a.w) + bf2f(b.w) + bf2f(r.w) + g.w;
  ((float4*)out)[i4] = o;
}

// ---------------------------------------------------------------- Attention
// (unchanged from round 9 — verified)
__global__ __launch_bounds__(256) void attn_fwd(
    const ushort* __restrict__ qb, const ushort* __restrict__ kb,
    const ushort* __restrict__ vTb, ushort* __restrict__ ob) {
  extern __shared__ __align__(16) ushort asm_[];
  ushort* KsB = asm_;            // 2 x [64][128]  (chunk ^= row&15)
  ushort* VsB = asm_ + 16384;    // 2 x [128][64]  (chunk ^= row&7)
  ushort* Pw  = asm_ + 32768 + (threadIdx.x >> 6) * 2048;  // [32][64]/wave

  int blk = blockIdx.x;
  int i15 = blk & 15;
  int qt = (blk & 256) ? i15 : 15 - i15;
  int bh = blk >> 4;
  int b = bh >> 4, h = bh & 15;
  int q0 = qt << 7;
  int t = threadIdx.x, lane = t & 63, w = t >> 6;
  int l31 = lane & 31, hi = lane >> 5;
  const size_t base = (size_t)b * SS * DD + (size_t)h * HDIM;
  const ushort* qp = qb + base;
  const ushort* kp = kb + base;
  const ushort* vp = vTb + (size_t)bh * HDIM * SS;   // V^T: [d][s]
  int wq0 = q0 + w * 32;
  int qg = wq0 + l31;

  bf16x8 qf[8];
  #pragma unroll
  for (int kk = 0; kk < 8; kk++)
    qf[kk] = *(const bf16x8*)(qp + (size_t)qg * DD + kk * 16 + hi * 8);

  auto stageKV = [&](int it, int buf) {
    int kv0 = it * 64;
    ushort* Kd = KsB + buf * 8192;
    ushort* Vd = VsB + buf * 8192;
    #pragma unroll
    for (int ii = 0; ii < 4; ii++) {
      int chunk = ii * 256 + t;
      int row = chunk >> 4, cc = chunk & 15;
      gload_lds16(kp + (size_t)(kv0 + row) * DD + ((cc ^ (row & 15)) << 3),
                  Kd + chunk * 8);
    }
    #pragma unroll
    for (int ii = 0; ii < 4; ii++) {
      int chunk = ii * 256 + t;
      int row = chunk >> 3, cc = chunk & 7;
      gload_lds16(vp + (size_t)row * SS + kv0 + ((cc ^ (row & 7)) << 3),
                  Vd + chunk * 8);
    }
  };

  f32x16 o[4] = {};
  float mu = -1e30f, lrow = 0.f;
  const float csc = 0.08838834764831845f * 1.4426950408889634f;

  int nIter = 2 * qt + 2;
  stageKV(0, 0);
  asm volatile("s_waitcnt vmcnt(0)" ::: "memory");
  __builtin_amdgcn_s_barrier();
  int cur = 0;
  for (int it = 0; it < nIter; ++it) {
    int kv0 = it * 64;
    if (it + 1 < nIter) stageKV(it + 1, cur ^ 1);

    if (kv0 <= wq0 + 31) {
      const ushort* Kc = KsB + cur * 8192;
      const ushort* Vc = VsB + cur * 8192;
      f32x16 s2[2] = {};
      #pragma unroll
      for (int nt = 0; nt < 2; nt++) {
        int row = nt * 32 + l31;
        #pragma unroll
        for (int kk = 0; kk < 8; kk++) {
          bf16x8 kf = *(const bf16x8*)
              &Kc[row * 128 + (((kk * 2 + hi) ^ (row & 15)) << 3)];
          s2[nt] = __builtin_amdgcn_mfma_f32_32x32x16_bf16(kf, qf[kk], s2[nt],
                                                           0, 0, 0);
        }
      }
      bool full = (kv0 + 63 <= wq0);
      float pm[4] = {-3e38f, -3e38f, -3e38f, -3e38f};
      if (full) {
        #pragma unroll
        for (int nt = 0; nt < 2; nt++)
          #pragma unroll
          for (int g2 = 0; g2 < 4; g2++)
            #pragma unroll
            for (int i = 0; i < 4; i++) {
              float u = s2[nt][g2 * 4 + i] * csc;
              s2[nt][g2 * 4 + i] = u;
              pm[i] = fmaxf(pm[i], u);
            }
      } else {
        #pragma unroll
        for (int nt = 0; nt < 2; nt++)
          #pragma unroll
          for (int g2 = 0; g2 < 4; g2++)
            #pragma unroll
            for (int i = 0; i < 4; i++) {
              int kvl = nt * 32 + g2 * 8 + 4 * hi + i;
              float u = (kv0 + kvl > qg) ? -3e38f : s2[nt][g2 * 4 + i] * csc;
              s2[nt][g2 * 4 + i] = u;
              pm[i] = fmaxf(pm[i], u);
            }
      }
      float mx = fmaxf(fmaxf(pm[0], pm[1]), fmaxf(pm[2], pm[3]));
      mx = fmaxf(mx, __shfl_xor(mx, 32));
      if (!__all(mx - mu <= 8.0f)) {
        float mnew = fmaxf(mu, mx);
        float fr = exp2f(mu - mnew);
        mu = mnew;
        lrow *= fr;
        #pragma unroll
        for (int dt = 0; dt < 4; dt++)
          #pragma unroll
          for (int r = 0; r < 16; r++) o[dt][r] *= fr;
      }
      float ps[4] = {0.f, 0.f, 0.f, 0.f};
      #pragma unroll
      for (int nt = 0; nt < 2; nt++)
        #pragma unroll
        for (int g2 = 0; g2 < 4; g2++)
          #pragma unroll
          for (int i = 0; i < 4; i++) {
            float p = exp2f(s2[nt][g2 * 4 + i] - mu);
            s2[nt][g2 * 4 + i] = p;
            ps[i] += p;
          }
      float sum = (ps[0] + ps[1]) + (ps[2] + ps[3]);
      sum += __shfl_xor(sum, 32);
      lrow += sum;
      #pragma unroll
      for (int nt = 0; nt < 2; nt++) {
        #pragma unroll
        for (int g2 = 0; g2 < 4; g2++) {
          uint2 u;
          u.x = pkbf2(s2[nt][g2 * 4 + 0], s2[nt][g2 * 4 + 1]);
          u.y = pkbf2(s2[nt][g2 * 4 + 2], s2[nt][g2 * 4 + 3]);
          int cp = (nt * 4 + g2) ^ (l31 & 7);
          *(uint2*)&Pw[l31 * 64 + cp * 8 + hi * 4] = u;
        }
      }
      asm volatile("s_waitcnt lgkmcnt(0)" ::: "memory");
      #pragma unroll
      for (int kk = 0; kk < 4; kk++) {
        bf16x8 pf = *(const bf16x8*)
            &Pw[l31 * 64 + (((kk * 2 + hi) ^ (l31 & 7)) << 3)];
        #pragma unroll
        for (int dt = 0; dt < 4; dt++) {
          int drow = dt * 32 + l31;
          bf16x8 vf = *(const bf16x8*)
              &Vc[drow * 64 + (((kk * 2 + hi) ^ (drow & 7)) << 3)];
          o[dt] = __builtin_amdgcn_mfma_f32_32x32x16_bf16(vf, pf, o[dt],
                                                          0, 0, 0);
        }
      }
    }
    asm volatile("s_waitcnt vmcnt(0)" ::: "memory");
    __builtin_amdgcn_s_barrier();
    cur ^= 1;
  }

  float inv = 1.0f / lrow;
  #pragma unroll
  for (int dt = 0; dt < 4; dt++) {
    #pragma unroll
    for (int g2 = 0; g2 < 4; g2++) {
      uint2 u;
      u.x = pkbf2(o[dt][g2 * 4 + 0] * inv, o[dt][g2 * 4 + 1] * inv);
      u.y = pkbf2(o[dt][g2 * 4 + 2] * inv, o[dt][g2 * 4 + 3] * inv);
      int d = dt * 32 + 8 * g2 + 4 * hi;
      *(uint2*)&ob[base + (size_t)qg * DD + d] = u;
    }
  }
}

// ---------------------------------------------------------------- launch
extern "C" void kernel_launch(void* const* d_in, const int* in_sizes, int n_in,
                              void* d_out, int out_size, void* d_ws,
                              size_t ws_size, hipStream_t stream) {
  const float* x    = (const float*)d_in[0];
  const float* Wq   = (const float*)d_in[1];
  const float* bq   = (const float*)d_in[2];
  const float* Wk   = (const float*)d_in[3];
  const float* bk   = (const float*)d_in[4];
  const float* Wv   = (const float*)d_in[5];
  const float* bv   = (const float*)d_in[6];
  const float* Wo   = (const float*)d_in[7];
  const float* bo   = (const float*)d_in[8];
  const float* ln1g = (const float*)d_in[9];
  const float* ln1b = (const float*)d_in[10];
  const float* ln2g = (const float*)d_in[11];
  const float* ln2b = (const float*)d_in[12];
  const float* W1   = (const float*)d_in[13];
  const float* b1   = (const float*)d_in[14];
  const float* W2   = (const float*)d_in[15];
  const float* b2   = (const float*)d_in[16];

  char* ws = (char*)d_ws;
  // [0,64MB): Wqkv bf16 (24MB) + Wo (8MB, contiguous); later W1b+W2b (64MB)
  ushort* Wqkvb = (ushort*)(ws);                     // [6144][2048]
  ushort* Wob   = Wqkvb + (size_t)3 * DD * DD;
  ushort* W1b = (ushort*)(ws);                       // alias (after Wo GEMM)
  ushort* W2b = W1b + (size_t)D4 * DD;
  // [64,128MB): q | k | vT | aob bf16; later gb (gelu out)
  ushort* qkvb = (ushort*)(ws + 67108864);
  ushort* qbf = qkvb;
  ushort* kbf = qbf + (size_t)MM * DD;
  ushort* vTt = kbf + (size_t)MM * DD;               // V^T: [bh][d][s]
  ushort* aob = vTt + (size_t)MM * DD;
  ushort* gb  = (ushort*)(ws + 67108864);            // alias (after Wo GEMM)
  // [160,176MB): h bf16 / h2 bf16 (bf16 residual stream)
  ushort* hb  = (ushort*)(ws + 167772160);
  ushort* h2b = hb;                                  // alias (after Wo GEMM)
  // [176,208MB): pre-LN2 bf16 (16MB); later MLP-down partials (32MB)
  ushort* h2inB = (ushort*)(ws + 184549376);
  ushort* pD    = (ushort*)(ws + 184549376);         // alias (after LN2)
  float* out  = (float*)d_out;

  const int LDSB = 147456;   // gemm2: 3 x 48KB
  const int LDSC = 131072;   // gemm8: 2 x 64KB
  const int LDSA = 81920;    // attn
  (void)hipFuncSetAttribute((const void*)gemm2<3, false, false>,
                      hipFuncAttributeMaxDynamicSharedMemorySize, LDSB);
  (void)hipFuncSetAttribute((const void*)gemm2<1, false, true>,
                      hipFuncAttributeMaxDynamicSharedMemorySize, LDSB);
  (void)hipFuncSetAttribute((const void*)gemm8<1, true>,
                      hipFuncAttributeMaxDynamicSharedMemorySize, LDSC);
  (void)hipFuncSetAttribute((const void*)gemm8<4, false>,
                      hipFuncAttributeMaxDynamicSharedMemorySize, LDSC);
  (void)hipFuncSetAttribute((const void*)attn_fwd,
                      hipFuncAttributeMaxDynamicSharedMemorySize, LDSA);

  dim3 blk(256);
  dim3 gblk(512);
  // 1. weight conversions, merged: Wq|Wk|Wv|Wo -> contiguous bf16
  cvt4_f32_bf16<12><<<16384, blk, 0, stream>>>(Wq, Wk, Wv, Wo, Wqkvb);
  // 2. LN1 (f32 in) -> hb (bf16)
  ln_rows<false><<<MM, blk, 0, stream>>>(x, ln1g, ln1b, hb);
  // 3. fused QKV projection (gemm2, 768 blocks = 3 full rounds)
  gemm2<3, false, false><<<768, gblk, LDSB, stream>>>(
      hb, Wqkvb, bq, bk, bv, nullptr, qkvb, MM, 3 * DD, DD);
  // 4. causal attention
  attn_fwd<<<512, blk, LDSA, stream>>>(qbf, kbf, vTt, aob);
  // 5. Wo projection + residual (hb) -> h2inB bf16 (gemm2, 256 blocks)
  gemm2<1, false, true><<<256, gblk, LDSB, stream>>>(
      aob, Wob, bo, bo, bo, hb, h2inB, MM, DD, DD);
  // 6. LN2 (bf16 in) -> h2b (bf16)
  ln_rows<true><<<MM, blk, 0, stream>>>(h2inB, ln2g, ln2b, h2b);
  // 7. MLP weight conversions, merged: W1|W2 -> contiguous bf16
  cvt4_f32_bf16<14><<<32768, blk, 0, stream>>>(W1, W2, W2, W2, W1b);
  // 8. MLP up + GELU (gemm8 v5, 512 blocks = 2 full rounds)
  gemm8<1, true><<<512, gblk, LDSC, stream>>>(
      h2b, W1b, b1, gb, MM, D4, DD, DD);
  // 9. MLP down split-K x2 -> bf16 partials (gemm8 v5, 256 blocks)
  gemm8<4, false><<<256, gblk, LDSC, stream>>>(
      gb, W2b, b2, pD, MM, DD, D4, D4 / 2);
  // 10. combine partials + b2 + residual (h2b) -> out
  mlp_fin<<<MM * DD / 1024, blk, 0, stream>>>(pD, h2b, b2, out);
}

// Round 16
// 596.637 us; speedup vs baseline: 1.0145x; 1.0145x over previous
//
#include <hip/hip_runtime.h>
#include <hip/hip_bf16.h>
#include <math.h>

// Problem constants
#define DD   2048
#define SS   2048
#define HH   16
#define HDIM 128
#define BB   2
#define MM   4096   // B*S rows
#define D4   8192

using bf16x8 = __attribute__((ext_vector_type(8))) short;
using f32x4  = __attribute__((ext_vector_type(4))) float;
using f32x16 = __attribute__((ext_vector_type(16))) float;

__device__ __forceinline__ ushort f2bf(float x) {
  uint u = __builtin_bit_cast(uint, x);
  u += 0x7FFFu + ((u >> 16) & 1u);   // round-to-nearest-even
  return (ushort)(u >> 16);
}
__device__ __forceinline__ float bf2f(ushort u) {
  return __builtin_bit_cast(float, (uint)u << 16);
}
__device__ __forceinline__ uint pkbf2(float a, float b) {
  return (uint)f2bf(a) | ((uint)f2bf(b) << 16);
}

__device__ __forceinline__ float gelu_f(float v) {
  float u = 0.7978845608028654f * (v + 0.044715f * v * v * v);
  float e = __expf(2.0f * u);
  float th = 1.0f - 2.0f / (e + 1.0f);   // robust tanh (inf-safe)
  return 0.5f * v * (1.0f + th);
}

__device__ __forceinline__ void gload_lds16(const void* g, void* l) {
  __builtin_amdgcn_global_load_lds(
      (const __attribute__((address_space(1))) void*)g,
      (__attribute__((address_space(3))) void*)l, 16, 0, 0);
}

// ---------------------------------------------------------------- f32 -> bf16
// 4-way merged conversion; dst segments contiguous. SHIFT: blocks per seg.
template <int SHIFT>
__global__ __launch_bounds__(256) void cvt4_f32_bf16(
    const float* __restrict__ s0, const float* __restrict__ s1,
    const float* __restrict__ s2, const float* __restrict__ s3,
    ushort* __restrict__ dst) {
  int seg = blockIdx.x >> SHIFT;
  int i = ((blockIdx.x & ((1 << SHIFT) - 1)) << 8) + threadIdx.x;
  const float* src = (seg == 0) ? s0 : (seg == 1) ? s1 : (seg == 2) ? s2 : s3;
  float4 v = ((const float4*)src)[i];
  ushort4 o;
  o.x = f2bf(v.x); o.y = f2bf(v.y); o.z = f2bf(v.z); o.w = f2bf(v.w);
  ((ushort4*)dst)[((size_t)seg << (SHIFT + 8)) + i] = o;
}

// ---------------------------------------------------------------- LayerNorm
// one block per row; 8 contiguous elems/thread; bf16 output.
// BIN: input is bf16 (residual-stream), else f32.
template <bool BIN>
__global__ __launch_bounds__(256) void ln_rows(
    const void* __restrict__ inp, const float* __restrict__ gam,
    const float* __restrict__ bet, ushort* __restrict__ outb) {
  int row = blockIdx.x;
  int t = threadIdx.x;
  float v[8];
  if (BIN) {
    const ushort4* r4 = (const ushort4*)((const ushort*)inp + (size_t)row * DD);
    ushort4 a = r4[t * 2], b = r4[t * 2 + 1];
    v[0] = bf2f(a.x); v[1] = bf2f(a.y); v[2] = bf2f(a.z); v[3] = bf2f(a.w);
    v[4] = bf2f(b.x); v[5] = bf2f(b.y); v[6] = bf2f(b.z); v[7] = bf2f(b.w);
  } else {
    const float4* r4 = (const float4*)((const float*)inp + (size_t)row * DD);
    float4 a = r4[t * 2], b = r4[t * 2 + 1];
    v[0] = a.x; v[1] = a.y; v[2] = a.z; v[3] = a.w;
    v[4] = b.x; v[5] = b.y; v[6] = b.z; v[7] = b.w;
  }
  float s = ((v[0] + v[1]) + (v[2] + v[3])) + ((v[4] + v[5]) + (v[6] + v[7]));
  __shared__ float redA[4], redB[4];
  #pragma unroll
  for (int off = 32; off >= 1; off >>= 1) s += __shfl_xor(s, off);
  if ((t & 63) == 0) redA[t >> 6] = s;
  __syncthreads();
  float mean = (redA[0] + redA[1] + redA[2] + redA[3]) * (1.0f / DD);
  float q = 0.f;
  #pragma unroll
  for (int i = 0; i < 8; i++) { v[i] -= mean; q += v[i] * v[i]; }
  #pragma unroll
  for (int off = 32; off >= 1; off >>= 1) q += __shfl_xor(q, off);
  if ((t & 63) == 0) redB[t >> 6] = q;
  __syncthreads();
  float var = (redB[0] + redB[1] + redB[2] + redB[3]) * (1.0f / DD);
  float rstd = rsqrtf(var + 1e-5f);
  const float4* g4 = (const float4*)gam;
  const float4* b4 = (const float4*)bet;
  float4 g0 = g4[t * 2], g1 = g4[t * 2 + 1];
  float4 bb0 = b4[t * 2], bb1 = b4[t * 2 + 1];
  ushort4 u0, u1;
  u0.x = f2bf(v[0] * rstd * g0.x + bb0.x);
  u0.y = f2bf(v[1] * rstd * g0.y + bb0.y);
  u0.z = f2bf(v[2] * rstd * g0.z + bb0.z);
  u0.w = f2bf(v[3] * rstd * g0.w + bb0.w);
  u1.x = f2bf(v[4] * rstd * g1.x + bb1.x);
  u1.y = f2bf(v[5] * rstd * g1.y + bb1.y);
  u1.z = f2bf(v[6] * rstd * g1.z + bb1.z);
  u1.w = f2bf(v[7] * rstd * g1.w + bb1.w);
  ushort4* ob4 = (ushort4*)(outb + (size_t)row * DD);
  ob4[t * 2] = u0; ob4[t * 2 + 1] = u1;
}

// ---------------------------------------------------------------- GEMM (r3)
// C[M,N] = A[M,K](bf16) @ Bt[N,K](bf16)^T + bias (+bf16 res) (gelu)
// OMODE: 0 = f32 out, 1 = bf16 out, 3 = fused QKV routing.
// vmcnt-only tile wait. Verified r3..r14: 0 conflicts, ~850 TF.
template <int OMODE, bool GELU_, bool RES_>
__global__ __launch_bounds__(512, 2) void gemm2(
    const ushort* __restrict__ A, const ushort* __restrict__ Bt,
    const float* __restrict__ pb0, const float* __restrict__ pb1,
    const float* __restrict__ pb2, const ushort* __restrict__ res,
    void* __restrict__ Cout, int M, int N, int K) {
  extern __shared__ __align__(16) ushort smem[];   // 3 * (16384 + 8192)
  const int nbm = M >> 8, nbn = N >> 7;
  const int nwg = nbm * nbn;
  int wg = blockIdx.x;
  int wg2 = (wg & 7) * (nwg >> 3) + (wg >> 3);     // bijective XCD swizzle
  int bm = wg2 % nbm, bn = wg2 / nbm;
  int m0 = bm << 8, n0 = bn << 7;
  int t = threadIdx.x, lane = t & 63, w = t >> 6;
  int wm = w >> 2, wn = w & 3;
  int lr = lane & 15, lg = lane >> 4;

  auto stage = [&](int kt, int slot) {
    int k0 = kt << 6;
    ushort* lA = smem + slot * 24576;
    ushort* lB = lA + 16384;
    #pragma unroll
    for (int r = 0; r < 4; r++) {
      int idx = (r << 9) + t;
      int row = idx >> 3, ch = idx & 7;
      gload_lds16(A + (size_t)(m0 + row) * K + k0 + ((ch ^ (row & 7)) << 3),
                  lA + idx * 8);
    }
    #pragma unroll
    for (int r = 0; r < 2; r++) {
      int idx = (r << 9) + t;
      int row = idx >> 3, ch = idx & 7;
      gload_lds16(Bt + (size_t)(n0 + row) * K + k0 + ((ch ^ (row & 7)) << 3),
                  lB + idx * 8);
    }
  };

  f32x4 acc[8][2] = {};
  const int NT = K >> 6;
  stage(0, 0);
  stage(1, 1);
  int slot = 0;
  for (int kt = 0; kt < NT; ++kt) {
    __builtin_amdgcn_sched_barrier(0);
    if (kt + 1 < NT)
      asm volatile("s_waitcnt vmcnt(6)" ::: "memory");
    else
      asm volatile("s_waitcnt vmcnt(0)" ::: "memory");
    __builtin_amdgcn_s_barrier();
    __builtin_amdgcn_sched_barrier(0);
    if (kt + 2 < NT) {
      int s2 = slot + 2; if (s2 >= 3) s2 -= 3;
      stage(kt + 2, s2);
    }
    const ushort* lA = smem + slot * 24576;
    const ushort* lB = lA + 16384;
    bf16x8 af[8][2], bfr[2][2];
    #pragma unroll
    for (int mi = 0; mi < 8; mi++) {
      int row = wm * 128 + mi * 16 + lr;
      #pragma unroll
      for (int ks = 0; ks < 2; ks++)
        af[mi][ks] = *(const bf16x8*)
            &lA[row * 64 + (((ks * 4 + lg) ^ (row & 7)) << 3)];
    }
    #pragma unroll
    for (int ni = 0; ni < 2; ni++) {
      int row = wn * 32 + ni * 16 + lr;
      #pragma unroll
      for (int ks = 0; ks < 2; ks++)
        bfr[ni][ks] = *(const bf16x8*)
            &lB[row * 64 + (((ks * 4 + lg) ^ (row & 7)) << 3)];
    }
    __builtin_amdgcn_s_setprio(1);
    #pragma unroll
    for (int ks = 0; ks < 2; ks++)
      #pragma unroll
      for (int mi = 0; mi < 8; mi++)
        #pragma unroll
        for (int ni = 0; ni < 2; ni++)
          acc[mi][ni] = __builtin_amdgcn_mfma_f32_16x16x32_bf16(
              af[mi][ks], bfr[ni][ks], acc[mi][ni], 0, 0, 0);
    __builtin_amdgcn_s_setprio(0);
    slot = (slot + 1 == 3) ? 0 : slot + 1;
  }

  if (OMODE == 3) {
    // fused QKV routing; seg uniform per block (2048 % 128 == 0)
    int seg = n0 >> 11;
    const float* pb = (seg == 0) ? pb0 : (seg == 1) ? pb1 : pb2;
    int c0 = n0 & 2047;
    float bv[2];
    #pragma unroll
    for (int ni = 0; ni < 2; ni++) bv[ni] = pb[c0 + wn * 32 + ni * 16 + lr];
    if (seg < 2) {
      ushort* q_or_k = (ushort*)Cout + (size_t)seg * MM * DD;
      #pragma unroll
      for (int mi = 0; mi < 8; mi++) {
        #pragma unroll
        for (int r = 0; r < 4; r++) {
          int m = m0 + wm * 128 + mi * 16 + lg * 4 + r;
          #pragma unroll
          for (int ni = 0; ni < 2; ni++) {
            int col = c0 + wn * 32 + ni * 16 + lr;
            q_or_k[(size_t)m * DD + col] = f2bf(acc[mi][ni][r] + bv[ni]);
          }
        }
      }
    } else {
      // V^T: vT[(b*16+h)][d][s], ushort4 along s (4 consecutive m)
      ushort* vT = (ushort*)Cout + (size_t)2 * MM * DD;
      #pragma unroll
      for (int mi = 0; mi < 8; mi++) {
        int mg = m0 + wm * 128 + mi * 16 + lg * 4;
        int bb_ = mg >> 11, sb = mg & 2047;
        #pragma unroll
        for (int ni = 0; ni < 2; ni++) {
          int col = c0 + wn * 32 + ni * 16 + lr;
          int h = col >> 7, d = col & 127;
          ushort4 u4;
          u4.x = f2bf(acc[mi][ni][0] + bv[ni]);
          u4.y = f2bf(acc[mi][ni][1] + bv[ni]);
          u4.z = f2bf(acc[mi][ni][2] + bv[ni]);
          u4.w = f2bf(acc[mi][ni][3] + bv[ni]);
          size_t idx = ((size_t)(bb_ * 16 + h) * 128 + d) * 2048 + sb;
          *(ushort4*)&vT[idx] = u4;
        }
      }
    }
    return;
  }

  float bv[2];
  #pragma unroll
  for (int ni = 0; ni < 2; ni++) bv[ni] = pb0[n0 + wn * 32 + ni * 16 + lr];
  #pragma unroll
  for (int mi = 0; mi < 8; mi++) {
    #pragma unroll
    for (int r = 0; r < 4; r++) {
      int m = m0 + wm * 128 + mi * 16 + lg * 4 + r;
      #pragma unroll
      for (int ni = 0; ni < 2; ni++) {
        int n = n0 + wn * 32 + ni * 16 + lr;
        size_t idx = (size_t)m * N + n;
        float v = acc[mi][ni][r] + bv[ni];
        if (RES_) v += bf2f(res[idx]);
        if (GELU_) v = gelu_f(v);
        if (OMODE == 1) ((ushort*)Cout)[idx] = f2bf(v);
        else            ((float*)Cout)[idx] = v;
      }
    }
  }
}

// ---------------------------------------------------------------- GEMM v8.4
// 256x256, 4 barriers/K-tile, NO intra-phase lgkm pins (compiler emits fine
// counted lgkmcnt and interleaves ds_read with MFMA inside each phase).
// Phase containment via sched_barrier(0) fences around each s_barrier.
// vmcnt(8) once per tile at P4 => tile kt+1 fully landed. Best measured
// (r14): 150 us @ MfmaUtil 39.5 on MLP-up.
#define MF16(MQ, NQ, BARR) \
  { _Pragma("unroll") for (int ks = 0; ks < 2; ks++) { \
    _Pragma("unroll") for (int fm = 0; fm < 4; fm++) { \
      _Pragma("unroll") for (int fn = 0; fn < 2; fn++) { \
        acc[MQ * 4 + fm][NQ * 2 + fn] = \
            __builtin_amdgcn_mfma_f32_16x16x32_bf16( \
                aR[fm][ks], BARR[fn][ks], acc[MQ * 4 + fm][NQ * 2 + fn], \
                0, 0, 0); } } } }

template <int OMODE, bool GELU_>
__global__ __launch_bounds__(512, 2) void gemm8(
    const ushort* __restrict__ A, const ushort* __restrict__ Bt,
    const float* __restrict__ pb0,
    void* __restrict__ Cout, int M, int N, int Kfull) {
  extern __shared__ __align__(16) ushort smem[];   // 65536 elem = 128 KB
  const int nbm = M >> 8, nbn = N >> 8;
  const int nwg = nbm * nbn;
  int wgr = blockIdx.x;
  int wg2 = (wgr & 7) * (nwg >> 3) + (wgr >> 3);   // bijective XCD swizzle
  int bm = wg2 % nbm, bn = wg2 / nbm;
  int m0 = bm << 8, n0 = bn << 8;
  int t = threadIdx.x, lane = t & 63, w = t >> 6;
  int wm = w >> 2, wn = w & 3;
  int lr = lane & 15, lg = lane >> 4;

  // staging source bases (phase-consumption row remap, src pre-swizzle)
  int srow = t >> 3;
  int ssw = ((t & 7) ^ (srow & 7)) << 3;
  const ushort* pA1 = A + (size_t)(m0 + srow) * Kfull + ssw;
  const ushort* pB1 = Bt +
      (size_t)(n0 + (srow >> 5) * 64 + (srow & 31)) * Kfull + ssw;
  const size_t K32 = (size_t)32 * Kfull, K64 = (size_t)64 * Kfull,
               K128 = (size_t)128 * Kfull;
  ushort* dA = smem + t * 8;
  ushort* dB = smem + 16384 + t * 8;

  // stage half h of tile kt: h 0=A-first 1=A-second 2=B-first 3=B-second
  auto stage = [&](int kt, int h) {
    int boff = (kt & 1) << 15;
    size_t ko = (size_t)kt << 6;
    if (h < 2) {
      const ushort* g = pA1 + (size_t)h * K64 + ko;
      ushort* d = dA + boff + h * 8192;
      gload_lds16(g, d);
      gload_lds16(g + K128, d + 4096);
    } else {
      const ushort* g = pB1 + (size_t)(h - 2) * K32 + ko;
      ushort* d = dB + boff + (h - 2) * 8192;
      gload_lds16(g, d);
      gload_lds16(g + K128, d + 4096);
    }
  };

  int swz0 = (lg ^ (lr & 7)) << 3;
  int swz1 = ((4 + lg) ^ (lr & 7)) << 3;
  int arb[4], brb[2];
  #pragma unroll
  for (int f = 0; f < 4; f++) arb[f] = (wm * 64 + f * 16 + lr) * 64;
  #pragma unroll
  for (int f = 0; f < 2; f++) brb[f] = (wn * 32 + f * 16 + lr) * 64;

  f32x4 acc[8][4] = {};
  bf16x8 aR[4][2], bR0[2][2], bR1[2][2];
  const int NT = Kfull >> 6;

  stage(0, 0); stage(0, 1); stage(0, 2); stage(0, 3);
  stage(1, 0); stage(1, 1); stage(1, 2); stage(1, 3);
  asm volatile("s_waitcnt vmcnt(8)" ::: "memory");   // tile 0 landed
  __builtin_amdgcn_s_barrier();
  __builtin_amdgcn_sched_barrier(0);

  for (int kt = 0; kt < NT; ++kt) {
    const ushort* hA = smem + ((kt & 1) << 15);
    const ushort* hB = hA + 16384;
    bool st2 = (kt + 2 < NT);
    // ---- P1: read A-first + B-first; MFMA Q(0,0) (compiler interleaves)
    __builtin_amdgcn_s_setprio(1);
    #pragma unroll
    for (int f = 0; f < 4; f++) {
      aR[f][0] = *(const bf16x8*)&hA[arb[f] + swz0];
      aR[f][1] = *(const bf16x8*)&hA[arb[f] + swz1];
    }
    #pragma unroll
    for (int f = 0; f < 2; f++) {
      bR0[f][0] = *(const bf16x8*)&hB[brb[f] + swz0];
      bR0[f][1] = *(const bf16x8*)&hB[brb[f] + swz1];
    }
    MF16(0, 0, bR0);
    __builtin_amdgcn_s_setprio(0);
    __builtin_amdgcn_sched_barrier(0);
    __builtin_amdgcn_s_barrier();                    // BAR1 (frees h0,h2)
    __builtin_amdgcn_sched_barrier(0);
    // ---- P2: stage h0,h2(kt+2); read B-second; MFMA Q(0,1)
    if (st2) { stage(kt + 2, 0); stage(kt + 2, 2); }
    __builtin_amdgcn_s_setprio(1);
    #pragma unroll
    for (int f = 0; f < 2; f++) {
      bR1[f][0] = *(const bf16x8*)&hB[8192 + brb[f] + swz0];
      bR1[f][1] = *(const bf16x8*)&hB[8192 + brb[f] + swz1];
    }
    MF16(0, 1, bR1);
    __builtin_amdgcn_s_setprio(0);
    __builtin_amdgcn_sched_barrier(0);
    __builtin_amdgcn_s_barrier();                    // BAR2 (frees h3)
    __builtin_amdgcn_sched_barrier(0);
    // ---- P3: stage h3(kt+2); read A-second; MFMA Q(1,1)
    if (st2) stage(kt + 2, 3);
    __builtin_amdgcn_s_setprio(1);
    #pragma unroll
    for (int f = 0; f < 4; f++) {
      aR[f][0] = *(const bf16x8*)&hA[8192 + arb[f] + swz0];
      aR[f][1] = *(const bf16x8*)&hA[8192 + arb[f] + swz1];
    }
    MF16(1, 1, bR1);
    __builtin_amdgcn_s_setprio(0);
    __builtin_amdgcn_sched_barrier(0);
    __builtin_amdgcn_s_barrier();                    // BAR3 (frees h1)
    __builtin_amdgcn_sched_barrier(0);
    // ---- P4: stage h1(kt+2); MFMA Q(1,0) reg-only; vmcnt; BAR
    if (st2) stage(kt + 2, 1);
    __builtin_amdgcn_s_setprio(1);
    MF16(1, 0, bR0);
    __builtin_amdgcn_s_setprio(0);
    __builtin_amdgcn_sched_barrier(0);
    if (st2)              { asm volatile("s_waitcnt vmcnt(8)" ::: "memory"); }
    else if (kt + 1 < NT) { asm volatile("s_waitcnt vmcnt(0)" ::: "memory"); }
    __builtin_amdgcn_s_barrier();                    // BAR4 (kt+1 ready)
    __builtin_amdgcn_sched_barrier(0);
  }

  float bv[4];
  #pragma unroll
  for (int ni = 0; ni < 4; ni++) bv[ni] = pb0[n0 + wn * 64 + ni * 16 + lr];
  #pragma unroll
  for (int mi = 0; mi < 8; mi++) {
    #pragma unroll
    for (int r = 0; r < 4; r++) {
      int m = m0 + wm * 128 + mi * 16 + lg * 4 + r;
      #pragma unroll
      for (int ni = 0; ni < 4; ni++) {
        int n = n0 + wn * 64 + ni * 16 + lr;
        float v = acc[mi][ni][r] + bv[ni];
        if (GELU_) v = gelu_f(v);
        ((ushort*)Cout)[(size_t)m * N + n] = f2bf(v);
      }
    }
  }
}

// ---------------------------------------------------------------- Attention
// (unchanged from round 9 — verified)
__global__ __launch_bounds__(256) void attn_fwd(
    const ushort* __restrict__ qb, const ushort* __restrict__ kb,
    const ushort* __restrict__ vTb, ushort* __restrict__ ob) {
  extern __shared__ __align__(16) ushort asm_[];
  ushort* KsB = asm_;            // 2 x [64][128]  (chunk ^= row&15)
  ushort* VsB = asm_ + 16384;    // 2 x [128][64]  (chunk ^= row&7)
  ushort* Pw  = asm_ + 32768 + (threadIdx.x >> 6) * 2048;  // [32][64]/wave

  int blk = blockIdx.x;
  int i15 = blk & 15;
  int qt = (blk & 256) ? i15 : 15 - i15;
  int bh = blk >> 4;
  int b = bh >> 4, h = bh & 15;
  int q0 = qt << 7;
  int t = threadIdx.x, lane = t & 63, w = t >> 6;
  int l31 = lane & 31, hi = lane >> 5;
  const size_t base = (size_t)b * SS * DD + (size_t)h * HDIM;
  const ushort* qp = qb + base;
  const ushort* kp = kb + base;
  const ushort* vp = vTb + (size_t)bh * HDIM * SS;   // V^T: [d][s]
  int wq0 = q0 + w * 32;
  int qg = wq0 + l31;

  bf16x8 qf[8];
  #pragma unroll
  for (int kk = 0; kk < 8; kk++)
    qf[kk] = *(const bf16x8*)(qp + (size_t)qg * DD + kk * 16 + hi * 8);

  auto stageKV = [&](int it, int buf) {
    int kv0 = it * 64;
    ushort* Kd = KsB + buf * 8192;
    ushort* Vd = VsB + buf * 8192;
    #pragma unroll
    for (int ii = 0; ii < 4; ii++) {
      int chunk = ii * 256 + t;
      int row = chunk >> 4, cc = chunk & 15;
      gload_lds16(kp + (size_t)(kv0 + row) * DD + ((cc ^ (row & 15)) << 3),
                  Kd + chunk * 8);
    }
    #pragma unroll
    for (int ii = 0; ii < 4; ii++) {
      int chunk = ii * 256 + t;
      int row = chunk >> 3, cc = chunk & 7;
      gload_lds16(vp + (size_t)row * SS + kv0 + ((cc ^ (row & 7)) << 3),
                  Vd + chunk * 8);
    }
  };

  f32x16 o[4] = {};
  float mu = -1e30f, lrow = 0.f;
  const float csc = 0.08838834764831845f * 1.4426950408889634f;

  int nIter = 2 * qt + 2;
  stageKV(0, 0);
  asm volatile("s_waitcnt vmcnt(0)" ::: "memory");
  __builtin_amdgcn_s_barrier();
  int cur = 0;
  for (int it = 0; it < nIter; ++it) {
    int kv0 = it * 64;
    if (it + 1 < nIter) stageKV(it + 1, cur ^ 1);

    if (kv0 <= wq0 + 31) {
      const ushort* Kc = KsB + cur * 8192;
      const ushort* Vc = VsB + cur * 8192;
      f32x16 s2[2] = {};
      #pragma unroll
      for (int nt = 0; nt < 2; nt++) {
        int row = nt * 32 + l31;
        #pragma unroll
        for (int kk = 0; kk < 8; kk++) {
          bf16x8 kf = *(const bf16x8*)
              &Kc[row * 128 + (((kk * 2 + hi) ^ (row & 15)) << 3)];
          s2[nt] = __builtin_amdgcn_mfma_f32_32x32x16_bf16(kf, qf[kk], s2[nt],
                                                           0, 0, 0);
        }
      }
      bool full = (kv0 + 63 <= wq0);
      float pm[4] = {-3e38f, -3e38f, -3e38f, -3e38f};
      if (full) {
        #pragma unroll
        for (int nt = 0; nt < 2; nt++)
          #pragma unroll
          for (int g2 = 0; g2 < 4; g2++)
            #pragma unroll
            for (int i = 0; i < 4; i++) {
              float u = s2[nt][g2 * 4 + i] * csc;
              s2[nt][g2 * 4 + i] = u;
              pm[i] = fmaxf(pm[i], u);
            }
      } else {
        #pragma unroll
        for (int nt = 0; nt < 2; nt++)
          #pragma unroll
          for (int g2 = 0; g2 < 4; g2++)
            #pragma unroll
            for (int i = 0; i < 4; i++) {
              int kvl = nt * 32 + g2 * 8 + 4 * hi + i;
              float u = (kv0 + kvl > qg) ? -3e38f : s2[nt][g2 * 4 + i] * csc;
              s2[nt][g2 * 4 + i] = u;
              pm[i] = fmaxf(pm[i], u);
            }
      }
      float mx = fmaxf(fmaxf(pm[0], pm[1]), fmaxf(pm[2], pm[3]));
      mx = fmaxf(mx, __shfl_xor(mx, 32));
      if (!__all(mx - mu <= 8.0f)) {
        float mnew = fmaxf(mu, mx);
        float fr = exp2f(mu - mnew);
        mu = mnew;
        lrow *= fr;
        #pragma unroll
        for (int dt = 0; dt < 4; dt++)
          #pragma unroll
          for (int r = 0; r < 16; r++) o[dt][r] *= fr;
      }
      float ps[4] = {0.f, 0.f, 0.f, 0.f};
      #pragma unroll
      for (int nt = 0; nt < 2; nt++)
        #pragma unroll
        for (int g2 = 0; g2 < 4; g2++)
          #pragma unroll
          for (int i = 0; i < 4; i++) {
            float p = exp2f(s2[nt][g2 * 4 + i] - mu);
            s2[nt][g2 * 4 + i] = p;
            ps[i] += p;
          }
      float sum = (ps[0] + ps[1]) + (ps[2] + ps[3]);
      sum += __shfl_xor(sum, 32);
      lrow += sum;
      #pragma unroll
      for (int nt = 0; nt < 2; nt++) {
        #pragma unroll
        for (int g2 = 0; g2 < 4; g2++) {
          uint2 u;
          u.x = pkbf2(s2[nt][g2 * 4 + 0], s2[nt][g2 * 4 + 1]);
          u.y = pkbf2(s2[nt][g2 * 4 + 2], s2[nt][g2 * 4 + 3]);
          int cp = (nt * 4 + g2) ^ (l31 & 7);
          *(uint2*)&Pw[l31 * 64 + cp * 8 + hi * 4] = u;
        }
      }
      asm volatile("s_waitcnt lgkmcnt(0)" ::: "memory");
      #pragma unroll
      for (int kk = 0; kk < 4; kk++) {
        bf16x8 pf = *(const bf16x8*)
            &Pw[l31 * 64 + (((kk * 2 + hi) ^ (l31 & 7)) << 3)];
        #pragma unroll
        for (int dt = 0; dt < 4; dt++) {
          int drow = dt * 32 + l31;
          bf16x8 vf = *(const bf16x8*)
              &Vc[drow * 64 + (((kk * 2 + hi) ^ (drow & 7)) << 3)];
          o[dt] = __builtin_amdgcn_mfma_f32_32x32x16_bf16(vf, pf, o[dt],
                                                          0, 0, 0);
        }
      }
    }
    asm volatile("s_waitcnt vmcnt(0)" ::: "memory");
    __builtin_amdgcn_s_barrier();
    cur ^= 1;
  }

  float inv = 1.0f / lrow;
  #pragma unroll
  for (int dt = 0; dt < 4; dt++) {
    #pragma unroll
    for (int g2 = 0; g2 < 4; g2++) {
      uint2 u;
      u.x = pkbf2(o[dt][g2 * 4 + 0] * inv, o[dt][g2 * 4 + 1] * inv);
      u.y = pkbf2(o[dt][g2 * 4 + 2] * inv, o[dt][g2 * 4 + 3] * inv);
      int d = dt * 32 + 8 * g2 + 4 * hi;
      *(uint2*)&ob[base + (size_t)qg * DD + d] = u;
    }
  }
}

// ---------------------------------------------------------------- launch
extern "C" void kernel_launch(void* const* d_in, const int* in_sizes, int n_in,
                              void* d_out, int out_size, void* d_ws,
                              size_t ws_size, hipStream_t stream) {
  const float* x    = (const float*)d_in[0];
  const float* Wq   = (const float*)d_in[1];
  const float* bq   = (const float*)d_in[2];
  const float* Wk   = (const float*)d_in[3];
  const float* bk   = (const float*)d_in[4];
  const float* Wv   = (const float*)d_in[5];
  const float* bv   = (const float*)d_in[6];
  const float* Wo   = (const float*)d_in[7];
  const float* bo   = (const float*)d_in[8];
  const float* ln1g = (const float*)d_in[9];
  const float* ln1b = (const float*)d_in[10];
  const float* ln2g = (const float*)d_in[11];
  const float* ln2b = (const float*)d_in[12];
  const float* W1   = (const float*)d_in[13];
  const float* b1   = (const float*)d_in[14];
  const float* W2   = (const float*)d_in[15];
  const float* b2   = (const float*)d_in[16];

  char* ws = (char*)d_ws;
  // [0,64MB): Wqkv bf16 (24MB) + Wo (8MB, contiguous); later W1b+W2b (64MB)
  ushort* Wqkvb = (ushort*)(ws);                     // [6144][2048]
  ushort* Wob   = Wqkvb + (size_t)3 * DD * DD;
  ushort* W1b = (ushort*)(ws);                       // alias (after Wo GEMM)
  ushort* W2b = W1b + (size_t)D4 * DD;
  // [64,128MB): q | k | vT | aob bf16; later gb (gelu out)
  ushort* qkvb = (ushort*)(ws + 67108864);
  ushort* qbf = qkvb;
  ushort* kbf = qbf + (size_t)MM * DD;
  ushort* vTt = kbf + (size_t)MM * DD;               // V^T: [bh][d][s]
  ushort* aob = vTt + (size_t)MM * DD;
  ushort* gb  = (ushort*)(ws + 67108864);            // alias (after Wo GEMM)
  // [160,176MB): h bf16 / h2 bf16 (bf16 residual stream)
  ushort* hb  = (ushort*)(ws + 167772160);
  ushort* h2b = hb;                                  // alias (after Wo GEMM)
  // [176,208MB): pre-LN2 (bf16, 16MB)
  ushort* h2inB = (ushort*)(ws + 184549376);
  float* out  = (float*)d_out;

  const int LDSB = 147456;   // gemm2: 3 x 48KB
  const int LDSC = 131072;   // gemm8: 2 x 64KB
  const int LDSA = 81920;    // attn
  (void)hipFuncSetAttribute((const void*)gemm2<3, false, false>,
                      hipFuncAttributeMaxDynamicSharedMemorySize, LDSB);
  (void)hipFuncSetAttribute((const void*)gemm2<1, false, true>,
                      hipFuncAttributeMaxDynamicSharedMemorySize, LDSB);
  (void)hipFuncSetAttribute((const void*)gemm2<0, false, true>,
                      hipFuncAttributeMaxDynamicSharedMemorySize, LDSB);
  (void)hipFuncSetAttribute((const void*)gemm8<1, true>,
                      hipFuncAttributeMaxDynamicSharedMemorySize, LDSC);
  (void)hipFuncSetAttribute((const void*)attn_fwd,
                      hipFuncAttributeMaxDynamicSharedMemorySize, LDSA);

  dim3 blk(256);
  dim3 gblk(512);
  // 1. weight conversions, merged: Wq|Wk|Wv|Wo -> contiguous bf16
  cvt4_f32_bf16<12><<<16384, blk, 0, stream>>>(Wq, Wk, Wv, Wo, Wqkvb);
  // 2. LN1 (f32 in) -> hb (bf16)
  ln_rows<false><<<MM, blk, 0, stream>>>(x, ln1g, ln1b, hb);
  // 3. fused QKV projection (gemm2, 768 blocks = 3 full rounds)
  gemm2<3, false, false><<<768, gblk, LDSB, stream>>>(
      hb, Wqkvb, bq, bk, bv, nullptr, qkvb, MM, 3 * DD, DD);
  // 4. causal attention
  attn_fwd<<<512, blk, LDSA, stream>>>(qbf, kbf, vTt, aob);
  // 5. Wo projection + residual (hb) -> h2inB bf16 (gemm2, 256 blocks)
  gemm2<1, false, true><<<256, gblk, LDSB, stream>>>(
      aob, Wob, bo, bo, bo, hb, h2inB, MM, DD, DD);
  // 6. LN2 (bf16 in) -> h2b (bf16)
  ln_rows<true><<<MM, blk, 0, stream>>>(h2inB, ln2g, ln2b, h2b);
  // 7. MLP weight conversions, merged: W1|W2 -> contiguous bf16
  cvt4_f32_bf16<14><<<32768, blk, 0, stream>>>(W1, W2, W2, W2, W1b);
  // 8. MLP up + GELU (gemm8 v4, 512 blocks = 2 full rounds)
  gemm8<1, true><<<512, gblk, LDSC, stream>>>(
      h2b, W1b, b1, gb, MM, D4, DD);
  // 9. MLP down + residual (h2b) -> out (gemm2, 256 blocks)
  gemm2<0, false, true><<<256, gblk, LDSB, stream>>>(
      gb, W2b, b2, b2, b2, h2b, out, MM, DD, D4);
}